// Round 9
// baseline (72872.980 us; speedup 1.0000x reference)
//
#include <hip/hip_runtime.h>
#include <math.h>

#define T_DEC 256
#define KSA 4
#define KSD 5
#define SEGA 448   // 1792/KSA
#define SEGD 512   // 2560/KSD

__device__ __forceinline__ float sigf(float x) { return 1.0f / (1.0f + expf(-x)); }

// ---------------- mlen normalizer ----------------
__global__ void convert_mlen(const void* p, int* out) {
    int b = threadIdx.x;            // 32 threads
    const int* pi = (const int*)p;
    const float* pf = (const float*)p;
    __shared__ int mode;
    if (b == 0) {
        int i0 = pi[0], i1 = pi[1];
        float f0 = pf[0];
        if (i0 >= 1 && i0 <= 512 && i1 == 0) mode = 2;
        else if (i0 >= 1 && i0 <= 512) mode = 0;
        else if (f0 >= 1.0f && f0 <= 512.0f) mode = 1;
        else mode = 0;
    }
    __syncthreads();
    int v;
    if (mode == 2)      v = pi[2 * b];
    else if (mode == 1) v = (int)(pf[b] + 0.5f);
    else                v = pi[b];
    if (v < 1) v = 1;
    if (v > 256) v = 256;
    out[b] = v;
}

__global__ void zero_f(float* __restrict__ p, int n) {
    int i = blockIdx.x * blockDim.x + threadIdx.x;
    if (i < n) p[i] = 0.0f;
}

// ---------------- prologue ----------------
__global__ __launch_bounds__(256) void prenet_all(const float* __restrict__ inputs,
                                                  const float* __restrict__ W1,
                                                  const float* __restrict__ W2,
                                                  float* __restrict__ pre) {
    int r = blockIdx.x;            // 0..8191 ; t = r>>5, b = r&31
    int t = r >> 5, b = r & 31;
    int o = threadIdx.x;
    __shared__ float xs[80];
    __shared__ float h1[256];
    if (o < 80) xs[o] = (t == 0) ? 0.0f : inputs[((size_t)b * T_DEC + (t - 1)) * 80 + o];
    __syncthreads();
    {
        const float* wr = W1 + (size_t)o * 80;
        float s = 0.f;
        #pragma unroll 8
        for (int k = 0; k < 80; ++k) s = fmaf(xs[k], wr[k], s);
        h1[o] = fmaxf(s, 0.0f);
    }
    __syncthreads();
    {
        const float* wr = W2 + (size_t)o * 256;
        float s = 0.f;
        for (int k = 0; k < 256; k += 4) {
            float4 w = *reinterpret_cast<const float4*>(wr + k);
            s = fmaf(h1[k], w.x, s); s = fmaf(h1[k+1], w.y, s);
            s = fmaf(h1[k+2], w.z, s); s = fmaf(h1[k+3], w.w, s);
        }
        pre[(size_t)r * 256 + o] = fmaxf(s, 0.0f);
    }
}

// per-step prenet (fallback tier): computes pre for step tstep into pre_t
__global__ __launch_bounds__(256) void prenet_step(const float* __restrict__ inputs,
                                                   const float* __restrict__ W1,
                                                   const float* __restrict__ W2,
                                                   float* __restrict__ pre_t,
                                                   int tstep) {
    int b = blockIdx.x;
    int o = threadIdx.x;
    __shared__ float xs[80];
    __shared__ float h1[256];
    if (o < 80) xs[o] = (tstep == 0) ? 0.0f : inputs[((size_t)b * T_DEC + (tstep - 1)) * 80 + o];
    __syncthreads();
    {
        const float* wr = W1 + (size_t)o * 80;
        float s = 0.f;
        #pragma unroll 8
        for (int k = 0; k < 80; ++k) s = fmaf(xs[k], wr[k], s);
        h1[o] = fmaxf(s, 0.0f);
    }
    __syncthreads();
    {
        const float* wr = W2 + (size_t)o * 256;
        float s = 0.f;
        for (int k = 0; k < 256; k += 4) {
            float4 w = *reinterpret_cast<const float4*>(wr + k);
            s = fmaf(h1[k], w.x, s); s = fmaf(h1[k+1], w.y, s);
            s = fmaf(h1[k+2], w.z, s); s = fmaf(h1[k+3], w.w, s);
        }
        pre_t[(size_t)b * 256 + o] = fmaxf(s, 0.0f);
    }
}

__global__ __launch_bounds__(128) void proc_mem(const float* __restrict__ mem,
                                                const float* __restrict__ Wm,
                                                float* __restrict__ pm) {
    int r = blockIdx.x;
    int d = threadIdx.x;
    __shared__ float xs[512];
    for (int k = d; k < 512; k += 128) xs[k] = mem[(size_t)r * 512 + k];
    __syncthreads();
    const float* wr = Wm + (size_t)d * 512;
    float s = 0.f;
    for (int k = 0; k < 512; k += 4) {
        float4 w = *reinterpret_cast<const float4*>(wr + k);
        s = fmaf(xs[k], w.x, s); s = fmaf(xs[k+1], w.y, s);
        s = fmaf(xs[k+2], w.z, s); s = fmaf(xs[k+3], w.w, s);
    }
    pm[(size_t)r * 128 + d] = s;
}

__global__ __launch_bounds__(256) void transpose_wq(const float* __restrict__ Wq,
                                                    float* __restrict__ wqT) {
    int i = blockIdx.x * 256 + threadIdx.x;
    int d = i & 127, k = i >> 7;
    wqT[i] = Wq[(size_t)d * 1024 + k];
}

// ---------------- kgemm: register-tiled, LDS-free, k-split ----------------
// Thread tile: 2 batch x 8 rows. Per 4-k: 2 X float4 + 8 W float4 + 64 FMA.
__device__ __forceinline__ void gemm_region(
    const float* __restrict__ xbase, int xstr,
    const float* __restrict__ wbase, int wstr, int wc0,
    int g0, int g1, int kb, int ke,
    int b0, int r0, float acc[2][8])
{
    int lo = kb > g0 ? kb : g0;
    int hi = ke < g1 ? ke : g1;
    if (lo >= hi) return;
    const float* xp0 = xbase + (size_t)b0 * xstr + (lo - g0);
    const float* xp1 = xp0 + xstr;
    const float* wp[8];
    #pragma unroll
    for (int j = 0; j < 8; ++j)
        wp[j] = wbase + (size_t)(r0 + j) * wstr + (lo - wc0);
    for (int k = lo; k < hi; k += 4) {
        float4 xa = *reinterpret_cast<const float4*>(xp0); xp0 += 4;
        float4 xb = *reinterpret_cast<const float4*>(xp1); xp1 += 4;
        #pragma unroll
        for (int j = 0; j < 8; ++j) {
            float4 w = *reinterpret_cast<const float4*>(wp[j]); wp[j] += 4;
            acc[0][j] = fmaf(xa.x, w.x, fmaf(xa.y, w.y, fmaf(xa.z, w.z, fmaf(xa.w, w.w, acc[0][j]))));
            acc[1][j] = fmaf(xb.x, w.x, fmaf(xb.y, w.y, fmaf(xb.z, w.z, fmaf(xb.w, w.w, acc[1][j]))));
        }
    }
}

__global__ __launch_bounds__(128) void kgemm(
    const float* __restrict__ WihA, const float* __restrict__ WhhA,
    const float* __restrict__ WihD, const float* __restrict__ WhhD,
    const float* __restrict__ preT,   // pre(t+1), 32 rows stride 256
    const float* __restrict__ ctx,    // ctx(t), stride 512
    const float* __restrict__ hAc,    // h_a(t), stride 1024
    const float* __restrict__ hDp,    // h_d(t-1), stride 1024
    float* __restrict__ partA, float* __restrict__ partD,
    int do_a, int do_d)
{
    int blk = blockIdx.x;
    int tid = threadIdx.x;
    int b0 = (tid & 15) * 2;
    int rq = tid >> 4;                 // 0..7
    float acc[2][8];
    #pragma unroll
    for (int i = 0; i < 2; ++i)
        #pragma unroll
        for (int j = 0; j < 8; ++j) acc[i][j] = 0.f;
    float* p;
    if (blk < 256) {
        if (!do_a) return;
        int rt = blk >> 2, ks = blk & 3;
        int kb = ks * SEGA, ke = kb + SEGA;
        int r0 = rt * 64 + rq * 8;
        gemm_region(preT, 256, WihA, 768, 0,     0,   256,  kb, ke, b0, r0, acc);
        gemm_region(ctx,  512, WihA, 768, 0,     256, 768,  kb, ke, b0, r0, acc);
        gemm_region(hAc, 1024, WhhA, 1024, 768,  768, 1792, kb, ke, b0, r0, acc);
        p = partA + ((size_t)(ks * 32 + b0) * 4096 + r0);
    } else {
        if (!do_d) return;
        int bb = blk - 256;
        int rt = bb / 5, ks = bb % 5;
        int kb = ks * SEGD, ke = kb + SEGD;
        int r0 = rt * 64 + rq * 8;
        gemm_region(hAc, 1024, WihD, 1536, 0,     0,    1024, kb, ke, b0, r0, acc);
        gemm_region(ctx,  512, WihD, 1536, 0,     1024, 1536, kb, ke, b0, r0, acc);
        gemm_region(hDp, 1024, WhhD, 1024, 1536,  1536, 2560, kb, ke, b0, r0, acc);
        p = partD + ((size_t)(ks * 32 + b0) * 4096 + r0);
    }
    *reinterpret_cast<float4*>(p)     = make_float4(acc[0][0], acc[0][1], acc[0][2], acc[0][3]);
    *reinterpret_cast<float4*>(p + 4) = make_float4(acc[0][4], acc[0][5], acc[0][6], acc[0][7]);
    float* p1 = p + 4096;
    *reinterpret_cast<float4*>(p1)     = make_float4(acc[1][0], acc[1][1], acc[1][2], acc[1][3]);
    *reinterpret_cast<float4*>(p1 + 4) = make_float4(acc[1][4], acc[1][5], acc[1][6], acc[1][7]);
}

// ---------------- kgates: reduce k-split partials + LSTM nonlinearity ------
__global__ __launch_bounds__(256) void kgates(
    const float* __restrict__ bA, const float* __restrict__ bD,
    const float* __restrict__ partA, const float* __restrict__ partD,
    float* __restrict__ cA, float* __restrict__ cD,
    float* __restrict__ hAout, float* __restrict__ hDout,
    int do_a, int do_d)
{
    int i = blockIdx.x * 256 + threadIdx.x;   // 0..65535
    int isD = i >> 15;
    int b = (i >> 10) & 31;
    int u = i & 1023;
    if (isD ? !do_d : !do_a) return;
    const float* part = isD ? partD : partA;
    const float* bias = isD ? bD : bA;
    int nks = isD ? KSD : KSA;
    float z[4];
    #pragma unroll
    for (int g = 0; g < 4; ++g) {
        float s = bias[g * 1024 + u];
        for (int ks = 0; ks < nks; ++ks)
            s += part[(size_t)(ks * 32 + b) * 4096 + g * 1024 + u];
        z[g] = s;
    }
    float* c = isD ? cD : cA;
    float* h = isD ? hDout : hAout;
    int idx = b * 1024 + u;
    float cn = sigf(z[1]) * c[idx] + sigf(z[0]) * tanhf(z[2]);
    float hn = sigf(z[3]) * tanhf(cn);
    c[idx] = cn;
    h[idx] = hn;
}

// ---------------- K_PA: proj(t) [blocks 0..31] + attn(t+1) [blocks 32..63] --
__global__ __launch_bounds__(256) void kpa(
    const float* __restrict__ enc, const float* __restrict__ pm,
    const float* __restrict__ wqT,
    const float* __restrict__ Wlc, const float* __restrict__ Wld,
    const float* __restrict__ vatt,
    const float* __restrict__ Wp, const float* __restrict__ bp,
    const float* __restrict__ Wg, const float* __restrict__ bg,
    const float* __restrict__ hA,      // h_a(t+1)
    const float* __restrict__ hD,      // h_d(t)
    const float* __restrict__ ctx_in,  // ctx(t)
    float* __restrict__ ctx_out,       // ctx(t+1)
    float* __restrict__ aw, float* __restrict__ cum,
    const int* __restrict__ mlen,
    float* __restrict__ mel, float* __restrict__ gate,
    float* __restrict__ align_out,
    int t, int do_proj, int do_attn)
{
    const int tid = threadIdx.x;
    if (blockIdx.x < 32) {
        if (!do_proj) return;
        int b = blockIdx.x;
        __shared__ float hc[1536];
        __shared__ float redp[164];
        for (int k = tid; k < 1024; k += 256) hc[k] = hD[(size_t)b * 1024 + k];
        for (int k = tid; k < 512; k += 256)  hc[1024 + k] = ctx_in[(size_t)b * 512 + k];
        __syncthreads();
        if (tid < 162) {
            int o = tid >> 1, hf = tid & 1;
            const float* wr = (o < 80) ? (Wp + (size_t)o * 1536) : Wg;
            float s = 0.f;
            int k0 = hf * 768;
            for (int k = k0; k < k0 + 768; k += 4) {
                float4 w = *reinterpret_cast<const float4*>(wr + k);
                s = fmaf(hc[k], w.x, s);   s = fmaf(hc[k+1], w.y, s);
                s = fmaf(hc[k+2], w.z, s); s = fmaf(hc[k+3], w.w, s);
            }
            redp[tid] = s;
        }
        __syncthreads();
        if (tid < 81) {
            float s = redp[2 * tid] + redp[2 * tid + 1];
            if (tid < 80) mel[((size_t)b * T_DEC + t) * 80 + tid] = s + bp[tid];
            else          gate[(size_t)b * T_DEC + t] = s + bg[0];
        }
        return;
    }
    if (!do_attn) return;
    int b = blockIdx.x - 32;
    int tt = t + 1;
    __shared__ float hs[1024];
    __shared__ float red[256];
    __shared__ float pqs[128];
    __shared__ float vs[128];
    __shared__ float aw0s[288], aw1s[288];
    __shared__ float wlc0[31][32], wlc1[31][32];
    __shared__ float wlds[128][36];
    __shared__ float sm[256];
    __shared__ float red4[4];
    for (int k = tid; k < 1024; k += 256) hs[k] = hA[(size_t)b * 1024 + k];
    for (int i = tid; i < 288; i += 256) {
        int pos = i - 16;
        float v0 = 0.f, v1 = 0.f;
        if (pos >= 0 && pos < 256) {
            v0 = aw[(size_t)b * 256 + pos];
            v1 = cum[(size_t)b * 256 + pos];
        }
        aw0s[i] = v0; aw1s[i] = v1;
    }
    for (int i = tid; i < 992; i += 256) {
        int k = i >> 5, f = i & 31;
        wlc0[k][f] = Wlc[(size_t)f * 62 + k];
        wlc1[k][f] = Wlc[(size_t)f * 62 + 31 + k];
    }
    for (int i = tid; i < 4096; i += 256) wlds[i >> 5][i & 31] = Wld[i];
    if (tid < 128) vs[tid] = vatt[tid];
    __syncthreads();
    {
        int d = tid & 127, hf = tid >> 7;
        float s = 0.f;
        int k0 = hf * 512;
        for (int k = k0; k < k0 + 512; ++k)
            s = fmaf(hs[k], wqT[(size_t)k * 128 + d], s);
        red[tid] = s;
    }
    __syncthreads();
    if (tid < 128) pqs[tid] = red[tid] + red[tid + 128];
    __syncthreads();
    float cf[32];
    #pragma unroll
    for (int f = 0; f < 32; ++f) cf[f] = 0.f;
    for (int k = 0; k < 31; ++k) {
        float a0 = aw0s[tid + 1 + k], a1 = aw1s[tid + 1 + k];
        #pragma unroll
        for (int fq = 0; fq < 8; ++fq) {
            float4 w0 = *reinterpret_cast<const float4*>(&wlc0[k][fq << 2]);
            float4 w1 = *reinterpret_cast<const float4*>(&wlc1[k][fq << 2]);
            cf[fq*4+0] = fmaf(a0, w0.x, fmaf(a1, w1.x, cf[fq*4+0]));
            cf[fq*4+1] = fmaf(a0, w0.y, fmaf(a1, w1.y, cf[fq*4+1]));
            cf[fq*4+2] = fmaf(a0, w0.z, fmaf(a1, w1.z, cf[fq*4+2]));
            cf[fq*4+3] = fmaf(a0, w0.w, fmaf(a1, w1.w, cf[fq*4+3]));
        }
    }
    float e = 0.f;
    {
        const float* pmr = pm + ((size_t)b * 256 + tid) * 128;
        for (int d = 0; d < 128; ++d) {
            float loc = 0.f;
            #pragma unroll
            for (int fq = 0; fq < 8; ++fq) {
                float4 w = *reinterpret_cast<const float4*>(&wlds[d][fq << 2]);
                loc = fmaf(cf[fq*4+0], w.x, loc); loc = fmaf(cf[fq*4+1], w.y, loc);
                loc = fmaf(cf[fq*4+2], w.z, loc); loc = fmaf(cf[fq*4+3], w.w, loc);
            }
            float a = tanhf(pqs[d] + loc + pmr[d]);
            e = fmaf(a, vs[d], e);
        }
    }
    if (tid >= mlen[b]) e = -1e9f;
    float m = e;
    #pragma unroll
    for (int o = 32; o >= 1; o >>= 1) m = fmaxf(m, __shfl_xor(m, o));
    if ((tid & 63) == 0) red4[tid >> 6] = m;
    __syncthreads();
    m = fmaxf(fmaxf(red4[0], red4[1]), fmaxf(red4[2], red4[3]));
    __syncthreads();
    float p = expf(e - m);
    float s = p;
    #pragma unroll
    for (int o = 32; o >= 1; o >>= 1) s += __shfl_xor(s, o);
    if ((tid & 63) == 0) red4[tid >> 6] = s;
    __syncthreads();
    s = red4[0] + red4[1] + red4[2] + red4[3];
    float w = p / s;
    sm[tid] = w;
    aw[(size_t)b * 256 + tid] = w;
    cum[(size_t)b * 256 + tid] += w;
    align_out[((size_t)b * T_DEC + tt) * 256 + tid] = w;
    __syncthreads();
    for (int d = tid; d < 512; d += 256) {
        const float* mb = enc + (size_t)b * 256 * 512 + d;
        float s2 = 0.f;
        for (int p2 = 0; p2 < 256; ++p2) s2 = fmaf(sm[p2], mb[(size_t)p2 * 512], s2);
        ctx_out[(size_t)b * 512 + d] = s2;
    }
}

// ---------------- host ----------------
extern "C" void kernel_launch(void* const* d_in, const int* in_sizes, int n_in,
                              void* d_out, int out_size, void* d_ws, size_t ws_size,
                              hipStream_t stream) {
    const float* enc    = (const float*)d_in[0];
    const float* inputs = (const float*)d_in[1];
    const void*  mlen_raw = d_in[2];
    const float* W_pre1 = (const float*)d_in[3];
    const float* W_pre2 = (const float*)d_in[4];
    const float* Wih_a  = (const float*)d_in[5];
    const float* Whh_a  = (const float*)d_in[6];
    const float* b_a    = (const float*)d_in[7];
    const float* W_q    = (const float*)d_in[8];
    const float* W_mem  = (const float*)d_in[9];
    const float* Wlc    = (const float*)d_in[10];
    const float* Wld    = (const float*)d_in[11];
    const float* v_att  = (const float*)d_in[12];
    const float* Wih_d  = (const float*)d_in[13];
    const float* Whh_d  = (const float*)d_in[14];
    const float* b_d    = (const float*)d_in[15];
    const float* W_proj = (const float*)d_in[16];
    const float* b_proj = (const float*)d_in[17];
    const float* W_gate = (const float*)d_in[18];
    const float* b_gate = (const float*)d_in[19];

    // tiers: FULL has all-step prenet precomputed; MID computes prenet per step
    const size_t PRE_FULL = 2097152, PRE_MID = 8192;
    const size_t REST = 1048576 /*pm*/ + 131072 /*wqT*/ + 6 * 32768 /*h,c*/
                      + 2 * 8192 /*aw,cum*/ + 2 * 16384 /*ctx*/
                      + (size_t)KSA * 32 * 4096 /*partA*/
                      + (size_t)KSD * 32 * 4096 /*partD*/ + 32 /*mlen*/;
    bool full = ws_size >= (PRE_FULL + REST) * 4;
    bool mid  = ws_size >= (PRE_MID + REST) * 4;
    if (!full && !mid) return;   // diagnostic signature: 0.1455

    float* ws = (float*)d_ws;
    size_t o = 0;
    float* pre  = ws + o; o += full ? PRE_FULL : PRE_MID;
    float* pm   = ws + o; o += 1048576;
    float* wqT  = ws + o; o += 131072;
    size_t off_state = o;
    float* hA[2]; hA[0] = ws + o; o += 32768; hA[1] = ws + o; o += 32768;
    float* cA   = ws + o; o += 32768;
    float* hD[2]; hD[0] = ws + o; o += 32768; hD[1] = ws + o; o += 32768;
    float* cD   = ws + o; o += 32768;
    float* aw   = ws + o; o += 8192;
    float* cum  = ws + o; o += 8192;
    float* ctxP[2]; ctxP[0] = ws + o; o += 16384; ctxP[1] = ws + o; o += 16384;
    size_t state_len = o - off_state;          // zeroed every call
    float* partA = ws + o; o += (size_t)KSA * 32 * 4096;
    float* partD = ws + o; o += (size_t)KSD * 32 * 4096;
    int*   mlen  = (int*)(ws + o);

    float* out       = (float*)d_out;
    float* mel_out   = out;                               // 32*256*80
    float* gate_out  = out + (size_t)32 * 256 * 80;       // 32*256
    float* align_out = gate_out + (size_t)32 * 256;       // 32*256*256

    // prologue
    convert_mlen<<<1, 32, 0, stream>>>(mlen_raw, mlen);
    if (full) prenet_all<<<8192, 256, 0, stream>>>(inputs, W_pre1, W_pre2, pre);
    proc_mem<<<8192, 128, 0, stream>>>(enc, W_mem, pm);
    transpose_wq<<<512, 256, 0, stream>>>(W_q, wqT);
    zero_f<<<((int)state_len + 255) / 256, 256, 0, stream>>>(ws + off_state, (int)state_len);

    for (int t = -1; t <= 255; ++t) {
        int pc = t & 1;
        int pn = (t + 1) & 1;
        int do_a = (t < 255), do_d = (t >= 0);
        const float* preT;
        if (full) preT = pre + (size_t)(do_a ? (t + 1) : 0) * 8192;
        else {
            if (do_a) prenet_step<<<32, 256, 0, stream>>>(inputs, W_pre1, W_pre2, pre, t + 1);
            preT = pre;
        }
        kgemm<<<256 + 64 * KSD, 128, 0, stream>>>(Wih_a, Whh_a, Wih_d, Whh_d,
                                                  preT, ctxP[pc], hA[pc], hD[pn],
                                                  partA, partD, do_a, do_d);
        kgates<<<256, 256, 0, stream>>>(b_a, b_d, partA, partD, cA, cD,
                                        hA[pn], hD[pc], do_a, do_d);
        kpa<<<64, 256, 0, stream>>>(enc, pm, wqT, Wlc, Wld, v_att,
                                    W_proj, b_proj, W_gate, b_gate,
                                    hA[pn], hD[pc], ctxP[pc], ctxP[pn],
                                    aw, cum, mlen,
                                    mel_out, gate_out, align_out,
                                    t, t >= 0, t < 255);
    }
}